// Round 1
// baseline (171.909 us; speedup 1.0000x reference)
//
#include <hip/hip_runtime.h>
#include <hip/hip_bf16.h>
#include <stdint.h>

#define NROWS 2048
#define DIM   4096
#define NACT  684
#define INV_TEMP 10.0f

typedef __attribute__((ext_vector_type(4))) float floatx4;
typedef __attribute__((ext_vector_type(8))) short shortx8;

static __device__ __forceinline__ unsigned short f32_to_bf16(float f) {
  union { float f; unsigned int u; } v; v.f = f;
  unsigned int u = v.u;
  unsigned int r = u + 0x7fffu + ((u >> 16) & 1u);
  return (unsigned short)(r >> 16);
}

// Kernel 1: per-row L2 norm + bf16 convert of x/||x||.
// One block per row; 4096 floats = 1024 float4; 256 thr * 4 float4 each.
__global__ __launch_bounds__(256) void k_normconv(const float* __restrict__ X,
                                                  unsigned short* __restrict__ Y) {
  const int row = blockIdx.x;
  const float4* xr = (const float4*)(X + (size_t)row * DIM);
  float4 v[4];
  float s = 0.f;
#pragma unroll
  for (int t = 0; t < 4; t++) {
    float4 w = xr[threadIdx.x + t * 256];
    v[t] = w;
    s += w.x * w.x + w.y * w.y + w.z * w.z + w.w * w.w;
  }
#pragma unroll
  for (int off = 32; off > 0; off >>= 1) s += __shfl_down(s, off, 64);
  __shared__ float wsum[4];
  if ((threadIdx.x & 63) == 0) wsum[threadIdx.x >> 6] = s;
  __syncthreads();
  const float total = wsum[0] + wsum[1] + wsum[2] + wsum[3];
  const float inv = 1.0f / fmaxf(sqrtf(total), 1e-30f);
  ushort4* yr = (ushort4*)(Y + (size_t)row * DIM);
#pragma unroll
  for (int t = 0; t < 4; t++) {
    float4 w = v[t];
    ushort4 o;
    o.x = f32_to_bf16(w.x * inv);
    o.y = f32_to_bf16(w.y * inv);
    o.z = f32_to_bf16(w.z * inv);
    o.w = f32_to_bf16(w.w * inv);
    yr[threadIdx.x + t * 256] = o;
  }
}

// Kernel 2: S = (Y * Y^T) * 10, bf16 MFMA, 128x128 tile, BK=32, 256 thr (4 waves 2x2),
// global_load_lds width-16 staging (m97 structure).
__global__ __launch_bounds__(256) void k_gemm(const unsigned short* __restrict__ Y,
                                              float* __restrict__ S) {
  __shared__ __attribute__((aligned(16))) unsigned short sA[128 * 32];
  __shared__ __attribute__((aligned(16))) unsigned short sB[128 * 32];
  const int tid  = threadIdx.x;
  const int lane = tid & 63;
  const int wave = tid >> 6;
  const int wr = wave >> 1;
  const int wc = wave & 1;
  const int row0 = blockIdx.y * 128;
  const int col0 = blockIdx.x * 128;

  floatx4 zero = {0.f, 0.f, 0.f, 0.f};
  floatx4 acc[4][4];
#pragma unroll
  for (int i = 0; i < 4; i++)
#pragma unroll
    for (int j = 0; j < 4; j++) acc[i][j] = zero;

  // staging: thread t covers tile elements [t*8, t*8+8) (inst0) and [2048+t*8, ..) (inst1)
  const int sr = tid >> 2;         // row 0..63
  const int sc = (tid & 3) * 8;    // col 0,8,16,24
  const unsigned short* gA0 = Y + (size_t)(row0 + sr) * DIM + sc;
  const unsigned short* gA1 = gA0 + (size_t)64 * DIM;
  const unsigned short* gB0 = Y + (size_t)(col0 + sr) * DIM + sc;
  const unsigned short* gB1 = gB0 + (size_t)64 * DIM;

  const int fr = lane & 15;
  const int fc = (lane >> 4) * 8;

  for (int k0 = 0; k0 < DIM; k0 += 32) {
    __builtin_amdgcn_global_load_lds(
        (const __attribute__((address_space(1))) void*)(gA0 + k0),
        (__attribute__((address_space(3))) void*)(sA + tid * 8), 16, 0, 0);
    __builtin_amdgcn_global_load_lds(
        (const __attribute__((address_space(1))) void*)(gA1 + k0),
        (__attribute__((address_space(3))) void*)(sA + 2048 + tid * 8), 16, 0, 0);
    __builtin_amdgcn_global_load_lds(
        (const __attribute__((address_space(1))) void*)(gB0 + k0),
        (__attribute__((address_space(3))) void*)(sB + tid * 8), 16, 0, 0);
    __builtin_amdgcn_global_load_lds(
        (const __attribute__((address_space(1))) void*)(gB1 + k0),
        (__attribute__((address_space(3))) void*)(sB + 2048 + tid * 8), 16, 0, 0);
    __syncthreads();

    shortx8 af[4], bf[4];
#pragma unroll
    for (int mi = 0; mi < 4; mi++)
      af[mi] = *(const shortx8*)(sA + (wr * 64 + mi * 16 + fr) * 32 + fc);
#pragma unroll
    for (int ni = 0; ni < 4; ni++)
      bf[ni] = *(const shortx8*)(sB + (wc * 64 + ni * 16 + fr) * 32 + fc);
#pragma unroll
    for (int mi = 0; mi < 4; mi++)
#pragma unroll
      for (int ni = 0; ni < 4; ni++)
        acc[mi][ni] = __builtin_amdgcn_mfma_f32_16x16x32_bf16(af[mi], bf[ni], acc[mi][ni], 0, 0, 0);
    __syncthreads();
  }

  // C/D layout (16x16x32): col = lane&15, row = (lane>>4)*4 + reg
  const int cc  = lane & 15;
  const int cr4 = (lane >> 4) * 4;
#pragma unroll
  for (int mi = 0; mi < 4; mi++) {
    const int row = row0 + wr * 64 + mi * 16 + cr4;
#pragma unroll
    for (int ni = 0; ni < 4; ni++) {
      const int col = col0 + wc * 64 + ni * 16 + cc;
      float* dst = S + (size_t)row * NROWS + col;
#pragma unroll
      for (int r = 0; r < 4; r++) dst[(size_t)r * NROWS] = acc[mi][ni][r] * INV_TEMP;
    }
  }
}

// Kernel 3: T[i] = sum_b exp(S[i,b])
__global__ __launch_bounds__(256) void k_rowsum(const float* __restrict__ S,
                                                float* __restrict__ T) {
  const int row = blockIdx.x;
  const float* sr = S + (size_t)row * NROWS;
  float s = 0.f;
  for (int b = threadIdx.x; b < NROWS; b += 256) s += __expf(sr[b]);
#pragma unroll
  for (int off = 32; off > 0; off >>= 1) s += __shfl_down(s, off, 64);
  __shared__ float wsum[4];
  if ((threadIdx.x & 63) == 0) wsum[threadIdx.x >> 6] = s;
  __syncthreads();
  if (threadIdx.x == 0) T[row] = wsum[0] + wsum[1] + wsum[2] + wsum[3];
}

// Kernel 4: Dsum[p,k] = T[row] - sum_{j<160} exp(S[row, (a+4j)&2047]),
// row = (a+4k)&2047, a = 12*(p>>2)+(p&3). One wave per p.
__global__ __launch_bounds__(64) void k_dsum(const float* __restrict__ S,
                                             const float* __restrict__ T,
                                             float* __restrict__ Ds) {
  const int p = blockIdx.x;
  const int a = 12 * (p >> 2) + (p & 3);
  const int lane = threadIdx.x;
#pragma unroll
  for (int k = 0; k < 6; k++) {
    const int row = (a + 4 * k) & (NROWS - 1);
    const float* sr = S + (size_t)row * NROWS;
    float s = 0.f;
    for (int j = lane; j < 160; j += 64) s += __expf(sr[(a + 4 * j) & (NROWS - 1)]);
#pragma unroll
    for (int off = 32; off > 0; off >>= 1) s += __shfl_down(s, off, 64);
    if (lane == 0) Ds[p * 6 + k] = T[row] - s;
  }
}

// Kernel 5: total = sum over p, pairs of log(en+Da) + log(en+Db) - 2*num; out = total/3072
__global__ __launch_bounds__(256) void k_final(const float* __restrict__ S,
                                               const float* __restrict__ Ds,
                                               float* __restrict__ out) {
  const int pa[7] = {0, 1, 0, 3, 4, 1, 2};
  const int pb[7] = {1, 2, 3, 4, 5, 4, 5};
  float s = 0.f;
  for (int idx = threadIdx.x; idx < NACT * 7; idx += 256) {
    const int p = idx / 7;
    const int q = idx - p * 7;
    const int a0 = 12 * (p >> 2) + (p & 3);
    const int ra = (a0 + 4 * pa[q]) & (NROWS - 1);
    const int rb = (a0 + 4 * pb[q]) & (NROWS - 1);
    const float num = S[(size_t)ra * NROWS + rb];
    const float en = __expf(num);
    s += __logf(en + Ds[p * 6 + pa[q]]) + __logf(en + Ds[p * 6 + pb[q]]) - 2.f * num;
  }
#pragma unroll
  for (int off = 32; off > 0; off >>= 1) s += __shfl_down(s, off, 64);
  __shared__ float wsum[4];
  if ((threadIdx.x & 63) == 0) wsum[threadIdx.x >> 6] = s;
  __syncthreads();
  if (threadIdx.x == 0) out[0] = (wsum[0] + wsum[1] + wsum[2] + wsum[3]) / (6.0f * 512.0f);
}

extern "C" void kernel_launch(void* const* d_in, const int* in_sizes, int n_in,
                              void* d_out, int out_size, void* d_ws, size_t ws_size,
                              hipStream_t stream) {
  const float* X = (const float*)d_in[0];
  char* ws = (char*)d_ws;
  unsigned short* Y = (unsigned short*)ws;                              // 16 MB bf16
  float* S  = (float*)(ws + (size_t)16 * 1024 * 1024);                  // 16 MB fp32
  float* T  = (float*)(ws + (size_t)32 * 1024 * 1024);                  // 8 KB
  float* Ds = (float*)(ws + (size_t)32 * 1024 * 1024 + 8192);           // ~16.4 KB
  float* out = (float*)d_out;

  hipLaunchKernelGGL(k_normconv, dim3(NROWS), dim3(256), 0, stream, X, Y);
  hipLaunchKernelGGL(k_gemm, dim3(16, 16), dim3(256), 0, stream, Y, S);
  hipLaunchKernelGGL(k_rowsum, dim3(NROWS), dim3(256), 0, stream, S, T);
  hipLaunchKernelGGL(k_dsum, dim3(NACT), dim3(64), 0, stream, S, T, Ds);
  hipLaunchKernelGGL(k_final, dim3(1), dim3(256), 0, stream, S, Ds, out);
}

// Round 2
// 138.562 us; speedup vs baseline: 1.2407x; 1.2407x over previous
//
#include <hip/hip_runtime.h>
#include <hip/hip_bf16.h>
#include <stdint.h>

#define NROWS 2048
#define DIM   4096
#define NACT  684
#define INV_TEMP 10.0f
#define NTILE 136        // 16*17/2 upper-triangle 128x128 tiles
#define KSPLIT 8
#define KSEG  512        // DIM / KSPLIT

typedef __attribute__((ext_vector_type(4))) float floatx4;
typedef __attribute__((ext_vector_type(8))) short shortx8;
typedef __attribute__((ext_vector_type(8))) unsigned short ushortx8;

static __device__ __forceinline__ unsigned short f32_to_bf16(float f) {
  union { float f; unsigned int u; } v; v.f = f;
  unsigned int u = v.u;
  unsigned int r = u + 0x7fffu + ((u >> 16) & 1u);
  return (unsigned short)(r >> 16);
}
static __device__ __forceinline__ float bf16_to_f32(unsigned short u) {
  union { unsigned int u; float f; } v; v.u = ((unsigned int)u) << 16;
  return v.f;
}

// ---------------- Kernel 1: per-row L2 norm + bf16 convert ----------------
__global__ __launch_bounds__(256) void k_normconv(const float* __restrict__ X,
                                                  unsigned short* __restrict__ Y) {
  const int row = blockIdx.x;
  const float4* xr = (const float4*)(X + (size_t)row * DIM);
  float4 v[4];
  float s = 0.f;
#pragma unroll
  for (int t = 0; t < 4; t++) {
    float4 w = xr[threadIdx.x + t * 256];
    v[t] = w;
    s += w.x * w.x + w.y * w.y + w.z * w.z + w.w * w.w;
  }
#pragma unroll
  for (int off = 32; off > 0; off >>= 1) s += __shfl_down(s, off, 64);
  __shared__ float wsum[4];
  if ((threadIdx.x & 63) == 0) wsum[threadIdx.x >> 6] = s;
  __syncthreads();
  const float total = wsum[0] + wsum[1] + wsum[2] + wsum[3];
  const float inv = 1.0f / fmaxf(sqrtf(total), 1e-30f);
  ushort4* yr = (ushort4*)(Y + (size_t)row * DIM);
#pragma unroll
  for (int t = 0; t < 4; t++) {
    float4 w = v[t];
    ushort4 o;
    o.x = f32_to_bf16(w.x * inv);
    o.y = f32_to_bf16(w.y * inv);
    o.z = f32_to_bf16(w.z * inv);
    o.w = f32_to_bf16(w.w * inv);
    yr[threadIdx.x + t * 256] = o;
  }
}

// ------- Kernel 2A: symmetric split-K GEMM, bf16 partials (path A) --------
// grid (NTILE, KSPLIT). tile t -> (ti<=tj). Each block: 128x128 x K=512.
__global__ __launch_bounds__(256) void k_gemm_sym(const unsigned short* __restrict__ Y,
                                                  unsigned short* __restrict__ P) {
  __shared__ __attribute__((aligned(16))) unsigned short sA[128 * 32];
  __shared__ __attribute__((aligned(16))) unsigned short sB[128 * 32];
  const int t = blockIdx.x;
  const int kz = blockIdx.y;
  int ti = 0, rem = t;
  while (rem >= 16 - ti) { rem -= 16 - ti; ti++; }
  const int tj = ti + rem;
  const int row0 = ti * 128;
  const int col0 = tj * 128;
  const int kbase = kz * KSEG;

  const int tid  = threadIdx.x;
  const int lane = tid & 63;
  const int wave = tid >> 6;
  const int wr = wave >> 1;
  const int wc = wave & 1;

  floatx4 zero = {0.f, 0.f, 0.f, 0.f};
  floatx4 acc[4][4];
#pragma unroll
  for (int i = 0; i < 4; i++)
#pragma unroll
    for (int j = 0; j < 4; j++) acc[i][j] = zero;

  const int sr = tid >> 2;
  const int sc = (tid & 3) * 8;
  const unsigned short* gA0 = Y + (size_t)(row0 + sr) * DIM + kbase + sc;
  const unsigned short* gA1 = gA0 + (size_t)64 * DIM;
  const unsigned short* gB0 = Y + (size_t)(col0 + sr) * DIM + kbase + sc;
  const unsigned short* gB1 = gB0 + (size_t)64 * DIM;

  const int fr = lane & 15;
  const int fc = (lane >> 4) * 8;

  for (int k0 = 0; k0 < KSEG; k0 += 32) {
    __builtin_amdgcn_global_load_lds(
        (const __attribute__((address_space(1))) void*)(gA0 + k0),
        (__attribute__((address_space(3))) void*)(sA + tid * 8), 16, 0, 0);
    __builtin_amdgcn_global_load_lds(
        (const __attribute__((address_space(1))) void*)(gA1 + k0),
        (__attribute__((address_space(3))) void*)(sA + 2048 + tid * 8), 16, 0, 0);
    __builtin_amdgcn_global_load_lds(
        (const __attribute__((address_space(1))) void*)(gB0 + k0),
        (__attribute__((address_space(3))) void*)(sB + tid * 8), 16, 0, 0);
    __builtin_amdgcn_global_load_lds(
        (const __attribute__((address_space(1))) void*)(gB1 + k0),
        (__attribute__((address_space(3))) void*)(sB + 2048 + tid * 8), 16, 0, 0);
    __syncthreads();

    shortx8 af[4], bf[4];
#pragma unroll
    for (int mi = 0; mi < 4; mi++)
      af[mi] = *(const shortx8*)(sA + (wr * 64 + mi * 16 + fr) * 32 + fc);
#pragma unroll
    for (int ni = 0; ni < 4; ni++)
      bf[ni] = *(const shortx8*)(sB + (wc * 64 + ni * 16 + fr) * 32 + fc);
#pragma unroll
    for (int mi = 0; mi < 4; mi++)
#pragma unroll
      for (int ni = 0; ni < 4; ni++)
        acc[mi][ni] = __builtin_amdgcn_mfma_f32_16x16x32_bf16(af[mi], bf[ni], acc[mi][ni], 0, 0, 0);
    __syncthreads();
  }

  unsigned short* dst = P + (size_t)(t * KSPLIT + kz) * 16384;
  const int cc  = lane & 15;
  const int cr4 = (lane >> 4) * 4;
#pragma unroll
  for (int mi = 0; mi < 4; mi++) {
    const int row = wr * 64 + mi * 16 + cr4;
#pragma unroll
    for (int ni = 0; ni < 4; ni++) {
      const int col = wc * 64 + ni * 16 + cc;
#pragma unroll
      for (int r = 0; r < 4; r++)
        dst[(size_t)(row + r) * 128 + col] = f32_to_bf16(acc[mi][ni][r]);
    }
  }
}

// ---- Kernel 3A: combine partials -> S (both triangles) + fused exp-rowsum T ----
// grid (NTILE), 256 thr. Thread: row r=tid>>1, col half h=tid&1 (64 cols).
__global__ __launch_bounds__(256) void k_combine(const unsigned short* __restrict__ P,
                                                 float* __restrict__ S,
                                                 float* __restrict__ T) {
  __shared__ float tile[128][129];
  const int t = blockIdx.x;
  int ti = 0, rem = t;
  while (rem >= 16 - ti) { rem -= 16 - ti; ti++; }
  const int tj = ti + rem;
  const int gr = ti * 128, gc = tj * 128;
  const int tid = threadIdx.x;
  const int r = tid >> 1;
  const int h = tid & 1;

  float acc[64];
#pragma unroll
  for (int j = 0; j < 64; j++) acc[j] = 0.f;
#pragma unroll
  for (int kz = 0; kz < KSPLIT; kz++) {
    const ushortx8* p = (const ushortx8*)(P + (size_t)(t * KSPLIT + kz) * 16384 + r * 128 + h * 64);
#pragma unroll
    for (int c = 0; c < 8; c++) {
      ushortx8 u = p[c];
#pragma unroll
      for (int e = 0; e < 8; e++) acc[c * 8 + e] += bf16_to_f32((unsigned short)u[e]);
    }
  }
  float rs = 0.f;
#pragma unroll
  for (int j = 0; j < 64; j++) {
    float v = acc[j] * INV_TEMP;
    acc[j] = v;
    tile[r][h * 64 + j] = v;
    rs += __expf(v);
  }
  floatx4* srow = (floatx4*)(S + (size_t)(gr + r) * NROWS + gc + h * 64);
#pragma unroll
  for (int c = 0; c < 16; c++) {
    floatx4 v4 = {acc[c * 4], acc[c * 4 + 1], acc[c * 4 + 2], acc[c * 4 + 3]};
    srow[c] = v4;
  }
  rs += __shfl_xor(rs, 1, 64);
  if (h == 0) atomicAdd(&T[gr + r], rs);

  if (ti != tj) {
    __syncthreads();
    const int mr = tid >> 1;   // original col
    const int mh = tid & 1;    // original row half
    float cs = 0.f;
    floatx4* srow2 = (floatx4*)(S + (size_t)(gc + mr) * NROWS + gr + mh * 64);
#pragma unroll
    for (int c = 0; c < 16; c++) {
      floatx4 w;
#pragma unroll
      for (int e = 0; e < 4; e++) {
        float v = tile[mh * 64 + c * 4 + e][mr];
        w[e] = v;
        cs += __expf(v);
      }
      srow2[c] = w;
    }
    cs += __shfl_xor(cs, 1, 64);
    if (mh == 0) atomicAdd(&T[gc + mr], cs);
  }
}

// ------------- Path B kernels (fallback when ws is small) -------------
__global__ __launch_bounds__(256) void k_gemm(const unsigned short* __restrict__ Y,
                                              float* __restrict__ S) {
  __shared__ __attribute__((aligned(16))) unsigned short sA[128 * 32];
  __shared__ __attribute__((aligned(16))) unsigned short sB[128 * 32];
  const int tid  = threadIdx.x;
  const int lane = tid & 63;
  const int wave = tid >> 6;
  const int wr = wave >> 1;
  const int wc = wave & 1;
  const int row0 = blockIdx.y * 128;
  const int col0 = blockIdx.x * 128;

  floatx4 zero = {0.f, 0.f, 0.f, 0.f};
  floatx4 acc[4][4];
#pragma unroll
  for (int i = 0; i < 4; i++)
#pragma unroll
    for (int j = 0; j < 4; j++) acc[i][j] = zero;

  const int sr = tid >> 2;
  const int sc = (tid & 3) * 8;
  const unsigned short* gA0 = Y + (size_t)(row0 + sr) * DIM + sc;
  const unsigned short* gA1 = gA0 + (size_t)64 * DIM;
  const unsigned short* gB0 = Y + (size_t)(col0 + sr) * DIM + sc;
  const unsigned short* gB1 = gB0 + (size_t)64 * DIM;

  const int fr = lane & 15;
  const int fc = (lane >> 4) * 8;

  for (int k0 = 0; k0 < DIM; k0 += 32) {
    __builtin_amdgcn_global_load_lds(
        (const __attribute__((address_space(1))) void*)(gA0 + k0),
        (__attribute__((address_space(3))) void*)(sA + tid * 8), 16, 0, 0);
    __builtin_amdgcn_global_load_lds(
        (const __attribute__((address_space(1))) void*)(gA1 + k0),
        (__attribute__((address_space(3))) void*)(sA + 2048 + tid * 8), 16, 0, 0);
    __builtin_amdgcn_global_load_lds(
        (const __attribute__((address_space(1))) void*)(gB0 + k0),
        (__attribute__((address_space(3))) void*)(sB + tid * 8), 16, 0, 0);
    __builtin_amdgcn_global_load_lds(
        (const __attribute__((address_space(1))) void*)(gB1 + k0),
        (__attribute__((address_space(3))) void*)(sB + 2048 + tid * 8), 16, 0, 0);
    __syncthreads();

    shortx8 af[4], bf[4];
#pragma unroll
    for (int mi = 0; mi < 4; mi++)
      af[mi] = *(const shortx8*)(sA + (wr * 64 + mi * 16 + fr) * 32 + fc);
#pragma unroll
    for (int ni = 0; ni < 4; ni++)
      bf[ni] = *(const shortx8*)(sB + (wc * 64 + ni * 16 + fr) * 32 + fc);
#pragma unroll
    for (int mi = 0; mi < 4; mi++)
#pragma unroll
      for (int ni = 0; ni < 4; ni++)
        acc[mi][ni] = __builtin_amdgcn_mfma_f32_16x16x32_bf16(af[mi], bf[ni], acc[mi][ni], 0, 0, 0);
    __syncthreads();
  }

  const int cc  = lane & 15;
  const int cr4 = (lane >> 4) * 4;
#pragma unroll
  for (int mi = 0; mi < 4; mi++) {
    const int row = row0 + wr * 64 + mi * 16 + cr4;
#pragma unroll
    for (int ni = 0; ni < 4; ni++) {
      const int col = col0 + wc * 64 + ni * 16 + cc;
      float* dst = S + (size_t)row * NROWS + col;
#pragma unroll
      for (int r = 0; r < 4; r++) dst[(size_t)r * NROWS] = acc[mi][ni][r] * INV_TEMP;
    }
  }
}

__global__ __launch_bounds__(256) void k_rowsum(const float* __restrict__ S,
                                                float* __restrict__ T) {
  const int row = blockIdx.x;
  const float* sr = S + (size_t)row * NROWS;
  float s = 0.f;
  for (int b = threadIdx.x; b < NROWS; b += 256) s += __expf(sr[b]);
#pragma unroll
  for (int off = 32; off > 0; off >>= 1) s += __shfl_down(s, off, 64);
  __shared__ float wsum[4];
  if ((threadIdx.x & 63) == 0) wsum[threadIdx.x >> 6] = s;
  __syncthreads();
  if (threadIdx.x == 0) T[row] = wsum[0] + wsum[1] + wsum[2] + wsum[3];
}

// ---------------- Kernel 4: Dsum, one wave per (p,k) ----------------
__global__ __launch_bounds__(64) void k_dsum(const float* __restrict__ S,
                                             const float* __restrict__ T,
                                             float* __restrict__ Ds) {
  const int p = blockIdx.x;
  const int k = blockIdx.y;
  const int a = 12 * (p >> 2) + (p & 3);
  const int lane = threadIdx.x;
  const int row = (a + 4 * k) & (NROWS - 1);
  const float* sr = S + (size_t)row * NROWS;
  float s = 0.f;
  for (int j = lane; j < 160; j += 64) s += __expf(sr[(a + 4 * j) & (NROWS - 1)]);
#pragma unroll
  for (int off = 32; off > 0; off >>= 1) s += __shfl_down(s, off, 64);
  if (lane == 0) Ds[p * 6 + k] = T[row] - s;
}

// ---------------- Kernel 5: pair losses, multi-block + atomic ----------------
__global__ __launch_bounds__(256) void k_final(const float* __restrict__ S,
                                               const float* __restrict__ Ds,
                                               float* __restrict__ out) {
  const int pa[7] = {0, 1, 0, 3, 4, 1, 2};
  const int pb[7] = {1, 2, 3, 4, 5, 4, 5};
  const int idx = blockIdx.x * 256 + threadIdx.x;
  float s = 0.f;
  if (idx < NACT * 7) {
    const int p = idx / 7;
    const int q = idx - p * 7;
    const int a0 = 12 * (p >> 2) + (p & 3);
    const int ra = (a0 + 4 * pa[q]) & (NROWS - 1);
    const int rb = (a0 + 4 * pb[q]) & (NROWS - 1);
    const float num = S[(size_t)ra * NROWS + rb];
    const float en = __expf(num);
    s = __logf(en + Ds[p * 6 + pa[q]]) + __logf(en + Ds[p * 6 + pb[q]]) - 2.f * num;
  }
#pragma unroll
  for (int off = 32; off > 0; off >>= 1) s += __shfl_down(s, off, 64);
  if ((threadIdx.x & 63) == 0) atomicAdd(out, s * (1.0f / (6.0f * 512.0f)));
}

extern "C" void kernel_launch(void* const* d_in, const int* in_sizes, int n_in,
                              void* d_out, int out_size, void* d_ws, size_t ws_size,
                              hipStream_t stream) {
  const float* X = (const float*)d_in[0];
  char* ws = (char*)d_ws;
  unsigned short* Y = (unsigned short*)ws;                      // 16 MB
  float* S = (float*)(ws + (size_t)16 * 1024 * 1024);           // 16 MB
  float* out = (float*)d_out;

  const size_t pOff = (size_t)32 * 1024 * 1024;
  const size_t pBytes = (size_t)NTILE * KSPLIT * 16384 * 2;     // 35.65 MB bf16 partials
  const size_t needA = pOff + pBytes + 8192 + NACT * 6 * 4 + 256;

  hipMemsetAsync(out, 0, sizeof(float), stream);
  hipLaunchKernelGGL(k_normconv, dim3(NROWS), dim3(256), 0, stream, X, Y);

  if (ws_size >= needA) {
    unsigned short* P = (unsigned short*)(ws + pOff);
    float* T  = (float*)(ws + pOff + pBytes);
    float* Ds = (float*)(ws + pOff + pBytes + 8192);
    hipMemsetAsync(T, 0, NROWS * sizeof(float), stream);
    hipLaunchKernelGGL(k_gemm_sym, dim3(NTILE, KSPLIT), dim3(256), 0, stream, Y, P);
    hipLaunchKernelGGL(k_combine, dim3(NTILE), dim3(256), 0, stream, P, S, T);
    hipLaunchKernelGGL(k_dsum, dim3(NACT, 6), dim3(64), 0, stream, S, T, Ds);
    hipLaunchKernelGGL(k_final, dim3((NACT * 7 + 255) / 256), dim3(256), 0, stream, S, Ds, out);
  } else {
    float* T  = (float*)(ws + pOff);
    float* Ds = (float*)(ws + pOff + 8192);
    hipLaunchKernelGGL(k_gemm, dim3(16, 16), dim3(256), 0, stream, Y, S);
    hipLaunchKernelGGL(k_rowsum, dim3(NROWS), dim3(256), 0, stream, S, T);
    hipLaunchKernelGGL(k_dsum, dim3(NACT, 6), dim3(64), 0, stream, S, T, Ds);
    hipLaunchKernelGGL(k_final, dim3((NACT * 7 + 255) / 256), dim3(256), 0, stream, S, Ds, out);
  }
}